// Round 9
// baseline (269.423 us; speedup 1.0000x reference)
//
#include <hip/hip_runtime.h>
#include <hip/hip_bf16.h>

#define N_NODES 10000
#define N_EDGES 100000
#define D 248
#define DP 256      // padded D
#define HDIM 512
#define NNZ 2480
#define LN_EPS 1e-5f
#define NPB 32      // nodes per mega-block

typedef __attribute__((ext_vector_type(8))) short bf16x8_t;
typedef __attribute__((ext_vector_type(4))) float f32x4_t;

__device__ __forceinline__ float bf2f(unsigned short u) {
  unsigned int x = ((unsigned int)u) << 16;
  return __builtin_bit_cast(float, x);
}
__device__ __forceinline__ unsigned short f2bf(float f) {
  return __builtin_bit_cast(unsigned short, __float2bfloat16(f));
}
__device__ __forceinline__ float bflo(unsigned int w) {
  return __builtin_bit_cast(float, w << 16);
}
__device__ __forceinline__ float bfhi(unsigned int w) {
  return __builtin_bit_cast(float, w & 0xFFFF0000u);
}
__device__ __forceinline__ void gload_lds16(const unsigned short* gp,
                                            unsigned short* lds_base) {
  __builtin_amdgcn_global_load_lds(
      (const __attribute__((address_space(1))) void*)gp,
      (__attribute__((address_space(3))) void*)lds_base, 16, 0, 0);
}

// ---------------------------------------------------------------------------
// Fused prep (unchanged from R8): feature+weight bf16 casts, deg zero,
// triple CSR by K (packed int2 {J<<16|I, C}).
// ---------------------------------------------------------------------------
#define CAST_BLOCKS (N_NODES + DP + HDIM + DP)
#define ZERO_BLOCKS 40
#define PREP_BLOCKS (CAST_BLOCKS + ZERO_BLOCKS + 1)

__device__ __forceinline__ void cast_row(const float* src, __hip_bfloat16* dst,
                                         int r, int sr, int sc, int dc) {
  for (int c = threadIdx.x; c < dc; c += 256) {
    float v = (r < sr && c < sc) ? src[(size_t)r * sc + c] : 0.f;
    dst[(size_t)r * dc + c] = __float2bfloat16(v);
  }
}

__global__ __launch_bounds__(256) void prep_kernel(
    const float* __restrict__ features, const float* __restrict__ W_msg,
    const float* __restrict__ W1, const float* __restrict__ W2,
    __hip_bfloat16* __restrict__ featB, __hip_bfloat16* __restrict__ WmB,
    __hip_bfloat16* __restrict__ W1B, __hip_bfloat16* __restrict__ W2B,
    int* __restrict__ deg,
    const int* __restrict__ Iv, const int* __restrict__ Jv,
    const int* __restrict__ Kv, const float* __restrict__ Cv,
    int* __restrict__ rsK, int2* __restrict__ trip) {
  const int b = blockIdx.x;
  if (b < N_NODES) {
    cast_row(features, featB, b, N_NODES, D, DP);
  } else if (b < N_NODES + DP) {
    cast_row(W_msg, WmB, b - N_NODES, D, D, DP);
  } else if (b < N_NODES + DP + HDIM) {
    cast_row(W1, W1B, b - N_NODES - DP, HDIM, D, DP);
  } else if (b < CAST_BLOCKS) {
    cast_row(W2, W2B, b - N_NODES - DP - HDIM, D, HDIM, HDIM);
  } else if (b < CAST_BLOCKS + ZERO_BLOCKS) {
    int i = (b - CAST_BLOCKS) * 256 + threadIdx.x;
    if (i < N_NODES) deg[i] = 0;
  } else {
    __shared__ int cnt[D];
    __shared__ int off[D];
    const int tid = threadIdx.x;
    for (int k = tid; k < D; k += 256) cnt[k] = 0;
    __syncthreads();
    for (int t = tid; t < NNZ; t += 256) atomicAdd(&cnt[Kv[t]], 1);
    __syncthreads();
    if (tid == 0) {
      int run = 0;
      for (int k = 0; k < D; k++) { off[k] = run; rsK[k] = run; run += cnt[k]; }
      rsK[D] = run;
    }
    __syncthreads();
    for (int t = tid; t < NNZ; t += 256) {
      int pos = atomicAdd(&off[Kv[t]], 1);
      trip[pos] = make_int2((Jv[t] << 16) | Iv[t], __float_as_int(Cv[t]));
    }
  }
}

// ---------------------------------------------------------------------------
// Edge CSR-by-target: histogram -> scan -> placement (unchanged)
// ---------------------------------------------------------------------------
__global__ __launch_bounds__(256) void hist_tgt(
    const int* __restrict__ ei, int* __restrict__ deg) {
  int e = blockIdx.x * 256 + threadIdx.x;
  if (e < N_EDGES) atomicAdd(&deg[ei[N_EDGES + e]], 1);
}

__global__ __launch_bounds__(256) void scan_deg(
    const int* __restrict__ deg, int* __restrict__ rs, int* __restrict__ woff) {
  __shared__ int part[256];
  const int t = threadIdx.x;
  const int base = t * 40;
  int sum = 0;
  for (int i = 0; i < 40; i++) {
    int idx = base + i;
    if (idx < N_NODES) sum += deg[idx];
  }
  part[t] = sum;
  __syncthreads();
  if (t == 0) {
    int run = 0;
    for (int i = 0; i < 256; i++) { int tmp = part[i]; part[i] = run; run += tmp; }
    rs[N_NODES] = run;
  }
  __syncthreads();
  int run = part[t];
  for (int i = 0; i < 40; i++) {
    int idx = base + i;
    if (idx < N_NODES) { rs[idx] = run; woff[idx] = run; run += deg[idx]; }
  }
}

__global__ __launch_bounds__(256) void place_edges(
    const int* __restrict__ ei, int* __restrict__ woff, int* __restrict__ esrc) {
  int e = blockIdx.x * 256 + threadIdx.x;
  if (e < N_EDGES) {
    int pos = atomicAdd(&woff[ei[N_EDGES + e]], 1);
    esrc[pos] = ei[e];
  }
}

// ---------------------------------------------------------------------------
// MEGA: per 32-node block, all in LDS, zero global intermediates:
//   gather G -> S = G@Wm^T -> bracket(agg) -> H1 = silu(agg@W1^T+b1)
//   -> H2 = H1@W2^T+b2 -> out = LN(features + H2)
// LDS (80 KB): [0,16K) G->agg | [16K,48K) F+S -> H1 -> H2 | [48K,80K) W chunk
// 2 blocks/CU (160 KB cap); weights streamed via global_load_lds.
// ---------------------------------------------------------------------------
__global__ __launch_bounds__(256, 2) void mega_kernel(
    const unsigned short* __restrict__ featB, const float* __restrict__ features,
    const int* __restrict__ rs, const int* __restrict__ esrc,
    const int* __restrict__ rsK, const int2* __restrict__ trip,
    const unsigned short* __restrict__ WmB, const unsigned short* __restrict__ W1B,
    const unsigned short* __restrict__ W2B,
    const float* __restrict__ b1, const float* __restrict__ b2,
    const float* __restrict__ gamma, const float* __restrict__ beta,
    float* __restrict__ out) {
  __shared__ __align__(16) unsigned char smem[81920];
  unsigned short* Gs  = (unsigned short*)smem;            // 32x256 bf16 (G, then agg)
  unsigned short* Fs  = (unsigned short*)(smem + 16384);  // 32x256 bf16 (featB rows)
  unsigned short* Ss  = (unsigned short*)(smem + 32768);  // 32x256 bf16 (S)
  unsigned short* Ws  = (unsigned short*)(smem + 49152);  // weight chunk (32 KB)
  unsigned short* H1s = (unsigned short*)(smem + 16384);  // 32x512 bf16 (over F+S)
  float*          H2s = (float*)(smem + 16384);           // 32x256 f32  (over H1)

  const int tid = threadIdx.x;
  const int wave = tid >> 6;
  const int lane = tid & 63;
  const int half = lane >> 5;
  const int c = lane & 31;
  const int ml = lane & 15;
  const int q = lane >> 4;
  const int n0 = blockIdx.x * NPB;

  // ---- stage F rows: 32 rows x 512 B = 16 insts (4/wave), 2 rows/inst
#pragma unroll
  for (int i = 0; i < 4; i++) {
    int t = wave * 4 + i;
    gload_lds16(featB + (size_t)(n0 + t * 2 + half) * DP + c * 8, Fs + t * 512);
  }

  // ---- gather G: each wave 8 nodes serial; two 32-lane halves interleave edges
  for (int i = 0; i < 8; i++) {
    const int li = wave * 8 + i;
    const int n = n0 + li;
    float a[8] = {0.f, 0.f, 0.f, 0.f, 0.f, 0.f, 0.f, 0.f};
    if (n < N_NODES) {
      const int beg = rs[n];
      const int dg = rs[n + 1] - beg;
      int eid = (lane < dg) ? esrc[beg + lane] : 0;
      const unsigned short* FBc = featB + (size_t)c * 8;
      int j = half;
      for (; j + 2 < dg && j < 64; j += 2) {
        int s = __shfl(eid, j);
        uint4 u = *(const uint4*)(FBc + (size_t)s * DP);
        a[0] += bflo(u.x); a[1] += bfhi(u.x);
        a[2] += bflo(u.y); a[3] += bfhi(u.y);
        a[4] += bflo(u.z); a[5] += bfhi(u.z);
        a[6] += bflo(u.w); a[7] += bfhi(u.w);
      }
      for (; j < dg; j += 2) {
        int s = (j < 64) ? __shfl(eid, j) : esrc[beg + j];
        uint4 u = *(const uint4*)(FBc + (size_t)s * DP);
        a[0] += bflo(u.x); a[1] += bfhi(u.x);
        a[2] += bflo(u.y); a[3] += bfhi(u.y);
        a[4] += bflo(u.z); a[5] += bfhi(u.z);
        a[6] += bflo(u.w); a[7] += bfhi(u.w);
      }
    }
#pragma unroll
    for (int v = 0; v < 8; v++) a[v] += __shfl_xor(a[v], 32);
    if (half == 0) {
      uint4 o;
      o.x = (unsigned)f2bf(a[0]) | ((unsigned)f2bf(a[1]) << 16);
      o.y = (unsigned)f2bf(a[2]) | ((unsigned)f2bf(a[3]) << 16);
      o.z = (unsigned)f2bf(a[4]) | ((unsigned)f2bf(a[5]) << 16);
      o.w = (unsigned)f2bf(a[6]) | ((unsigned)f2bf(a[7]) << 16);
      *(uint4*)(Gs + li * 256 + c * 8) = o;
    }
  }
  __syncthreads();  // F staged (vmcnt drained) + G complete

  // ---- Phase A: S = G @ Wm^T  (M=32, N=256, K=256; 4 chunks of K=64)
  {
    f32x4_t acc[2][4];
#pragma unroll
    for (int im = 0; im < 2; im++)
#pragma unroll
      for (int jn = 0; jn < 4; jn++) acc[im][jn] = (f32x4_t)0.f;
    for (int ch = 0; ch < 4; ch++) {
      const int k0 = ch * 64;
#pragma unroll
      for (int i = 0; i < 8; i++) {
        int t = wave * 8 + i;
        gload_lds16(WmB + (size_t)(t * 8 + (lane >> 3)) * DP + k0 + (lane & 7) * 8,
                    Ws + t * 512);
      }
      __syncthreads();
#pragma unroll
      for (int kk = 0; kk < 2; kk++) {
        bf16x8_t af[2], bf[4];
#pragma unroll
        for (int im = 0; im < 2; im++)
          af[im] = *(const bf16x8_t*)(Gs + (im * 16 + ml) * 256 + k0 + kk * 32 + q * 8);
#pragma unroll
        for (int jn = 0; jn < 4; jn++)
          bf[jn] = *(const bf16x8_t*)(Ws + (wave * 64 + jn * 16 + ml) * 64 + kk * 32 + q * 8);
#pragma unroll
        for (int im = 0; im < 2; im++)
#pragma unroll
          for (int jn = 0; jn < 4; jn++)
            acc[im][jn] = __builtin_amdgcn_mfma_f32_16x16x32_bf16(
                af[im], bf[jn], acc[im][jn], 0, 0, 0);
      }
      __syncthreads();
    }
    // S epilogue: row gm = im*16 + q*4 + reg, col gn = wave*64 + jn*16 + ml
#pragma unroll
    for (int im = 0; im < 2; im++)
#pragma unroll
      for (int jn = 0; jn < 4; jn++)
#pragma unroll
        for (int reg = 0; reg < 4; reg++)
          Ss[(im * 16 + q * 4 + reg) * 256 + wave * 64 + jn * 16 + ml] =
              f2bf(acc[im][jn][reg]);
  }
  __syncthreads();

  // ---- bracket: agg (into Gs) = sum_t C * S[I] * F[J], per row; no atomics
#pragma unroll
  for (int kk = 0; kk < 4; kk++) {
    const int k = lane + kk * 64;
    int tb = 0, te = 0;
    if (k < D) { tb = rsK[k]; te = rsK[k + 1]; }
    for (int i = 0; i < 8; i++) {
      const int r = wave * 8 + i;
      float a = 0.f;
      for (int t = tb; t < te; t++) {
        int2 tr = trip[t];
        a += __int_as_float(tr.y) * bf2f(Ss[r * 256 + (tr.x & 0xFFFF)]) *
             bf2f(Fs[r * 256 + (tr.x >> 16)]);
      }
      Gs[r * 256 + k] = f2bf(a);  // k in [D,DP) -> 0
    }
  }
  __syncthreads();

  // ---- Phase C: H1 = silu(agg @ W1^T + b1)  (M=32, N=512, K=256; 8 chunks of 32)
  {
    f32x4_t acc[2][8];
#pragma unroll
    for (int im = 0; im < 2; im++)
#pragma unroll
      for (int jn = 0; jn < 8; jn++) acc[im][jn] = (f32x4_t)0.f;
    for (int ch = 0; ch < 8; ch++) {
      const int k0 = ch * 32;
#pragma unroll
      for (int i = 0; i < 8; i++) {
        int t = wave * 8 + i;
        gload_lds16(W1B + (size_t)(t * 16 + (lane >> 2)) * DP + k0 + (lane & 3) * 8,
                    Ws + t * 512);
      }
      __syncthreads();
      bf16x8_t af[2], bf[8];
#pragma unroll
      for (int im = 0; im < 2; im++)
        af[im] = *(const bf16x8_t*)(Gs + (im * 16 + ml) * 256 + k0 + q * 8);
#pragma unroll
      for (int jn = 0; jn < 8; jn++)
        bf[jn] = *(const bf16x8_t*)(Ws + (wave * 128 + jn * 16 + ml) * 32 + q * 8);
#pragma unroll
      for (int im = 0; im < 2; im++)
#pragma unroll
        for (int jn = 0; jn < 8; jn++)
          acc[im][jn] = __builtin_amdgcn_mfma_f32_16x16x32_bf16(
              af[im], bf[jn], acc[im][jn], 0, 0, 0);
      __syncthreads();
    }
    // epilogue -> H1s (overwrites F+S, both dead since bracket barrier)
#pragma unroll
    for (int im = 0; im < 2; im++)
#pragma unroll
      for (int jn = 0; jn < 8; jn++) {
        const int gn = wave * 128 + jn * 16 + ml;
        const float bb = b1[gn];
#pragma unroll
        for (int reg = 0; reg < 4; reg++) {
          float v = acc[im][jn][reg] + bb;
          v = v / (1.f + __expf(-v));
          H1s[(im * 16 + q * 4 + reg) * 512 + gn] = f2bf(v);
        }
      }
  }
  __syncthreads();

  // ---- Phase D: H2 = H1 @ W2^T + b2  (M=32, N=256, K=512; 8 chunks of 64)
  {
    f32x4_t acc[2][4];
#pragma unroll
    for (int im = 0; im < 2; im++)
#pragma unroll
      for (int jn = 0; jn < 4; jn++) acc[im][jn] = (f32x4_t)0.f;
    for (int ch = 0; ch < 8; ch++) {
      const int k0 = ch * 64;
#pragma unroll
      for (int i = 0; i < 8; i++) {
        int t = wave * 8 + i;
        gload_lds16(W2B + (size_t)(t * 8 + (lane >> 3)) * HDIM + k0 + (lane & 7) * 8,
                    Ws + t * 512);
      }
      __syncthreads();
#pragma unroll
      for (int kk = 0; kk < 2; kk++) {
        bf16x8_t af[2], bf[4];
#pragma unroll
        for (int im = 0; im < 2; im++)
          af[im] = *(const bf16x8_t*)(H1s + (im * 16 + ml) * 512 + k0 + kk * 32 + q * 8);
#pragma unroll
        for (int jn = 0; jn < 4; jn++)
          bf[jn] = *(const bf16x8_t*)(Ws + (wave * 64 + jn * 16 + ml) * 64 + kk * 32 + q * 8);
#pragma unroll
        for (int im = 0; im < 2; im++)
#pragma unroll
          for (int jn = 0; jn < 4; jn++)
            acc[im][jn] = __builtin_amdgcn_mfma_f32_16x16x32_bf16(
                af[im], bf[jn], acc[im][jn], 0, 0, 0);
      }
      __syncthreads();  // also guarantees all H1 reads done before H2 overwrite
    }
    // epilogue -> H2s f32 (overwrites H1)
#pragma unroll
    for (int im = 0; im < 2; im++)
#pragma unroll
      for (int jn = 0; jn < 4; jn++) {
        const int gn = wave * 64 + jn * 16 + ml;
        const float bb = (gn < D) ? b2[gn] : 0.f;
#pragma unroll
        for (int reg = 0; reg < 4; reg++)
          H2s[(im * 16 + q * 4 + reg) * 256 + gn] = acc[im][jn][reg] + bb;
      }
  }
  __syncthreads();

  // ---- LN: wave per row (8 rows/wave), butterfly shfl
  for (int i = 0; i < 8; i++) {
    const int r = wave * 8 + i;
    const int n = n0 + r;
    if (n >= N_NODES) continue;  // wave-uniform
    float4 x = make_float4(0.f, 0.f, 0.f, 0.f);
    if (lane < 62) {
      float4 h = *(const float4*)(H2s + r * 256 + lane * 4);
      float4 f = *(const float4*)(features + (size_t)n * D + lane * 4);
      x = make_float4(f.x + h.x, f.y + h.y, f.z + h.z, f.w + h.w);
    }
    float s = x.x + x.y + x.z + x.w;
#pragma unroll
    for (int o = 32; o > 0; o >>= 1) s += __shfl_xor(s, o);
    const float mu = s * (1.f / (float)D);
    float4 xc = make_float4(x.x - mu, x.y - mu, x.z - mu, x.w - mu);
    float vv = 0.f;
    if (lane < 62) vv = xc.x * xc.x + xc.y * xc.y + xc.z * xc.z + xc.w * xc.w;
#pragma unroll
    for (int o = 32; o > 0; o >>= 1) vv += __shfl_xor(vv, o);
    const float rstd = rsqrtf(vv * (1.f / (float)D) + LN_EPS);
    if (lane < 62) {
      float4 g = *(const float4*)(gamma + lane * 4);
      float4 b = *(const float4*)(beta + lane * 4);
      float4 o;
      o.x = xc.x * rstd * g.x + b.x;
      o.y = xc.y * rstd * g.y + b.y;
      o.z = xc.z * rstd * g.z + b.z;
      o.w = xc.w * rstd * g.w + b.w;
      *(float4*)(out + (size_t)n * D + lane * 4) = o;
    }
  }
}

// ---------------------------------------------------------------------------
extern "C" void kernel_launch(void* const* d_in, const int* in_sizes, int n_in,
                              void* d_out, int out_size, void* d_ws, size_t ws_size,
                              hipStream_t stream) {
  const float* features = (const float*)d_in[0];
  const int*   ei       = (const int*)d_in[1];
  const float* W_msg    = (const float*)d_in[2];
  const float* W1       = (const float*)d_in[3];
  const float* b1       = (const float*)d_in[4];
  const float* W2       = (const float*)d_in[5];
  const float* b2       = (const float*)d_in[6];
  const float* gamma    = (const float*)d_in[7];
  const float* beta     = (const float*)d_in[8];
  const int*   Iv       = (const int*)d_in[9];
  const int*   Jv       = (const int*)d_in[10];
  const int*   Kv       = (const int*)d_in[11];
  const float* Cv       = (const float*)d_in[12];
  float* out = (float*)d_out;

  char* cur = (char*)d_ws;
  auto alloc = [&](size_t bytes) {
    char* p = cur;
    cur += (bytes + 255) & ~(size_t)255;
    return p;
  };
  __hip_bfloat16* featB = (__hip_bfloat16*)alloc((size_t)N_NODES * DP * 2);
  __hip_bfloat16* WmB   = (__hip_bfloat16*)alloc((size_t)DP * DP * 2);
  __hip_bfloat16* W1B   = (__hip_bfloat16*)alloc((size_t)HDIM * DP * 2);
  __hip_bfloat16* W2B   = (__hip_bfloat16*)alloc((size_t)DP * HDIM * 2);
  int*  rsK  = (int*)alloc((D + 1) * 4);
  int2* trip = (int2*)alloc(NNZ * 8);
  int*  deg  = (int*)alloc(N_NODES * 4);
  int*  rs   = (int*)alloc((N_NODES + 1) * 4);
  int*  woff = (int*)alloc(N_NODES * 4);
  int*  esrc = (int*)alloc(N_EDGES * 4);

  dim3 blk(256);

  // 1) prep: casts + deg zero + triple CSR
  prep_kernel<<<PREP_BLOCKS, blk, 0, stream>>>(
      features, W_msg, W1, W2, featB, WmB, W1B, W2B, deg,
      Iv, Jv, Kv, Cv, rsK, trip);
  // 2) edge CSR by target
  hist_tgt<<<(N_EDGES + 255) / 256, blk, 0, stream>>>(ei, deg);
  scan_deg<<<1, blk, 0, stream>>>(deg, rs, woff);
  place_edges<<<(N_EDGES + 255) / 256, blk, 0, stream>>>(ei, woff, esrc);
  // 3) mega: gather + GEMM1 + bracket + GEMM2 + GEMM3 + LN, all in LDS
  mega_kernel<<<(N_NODES + NPB - 1) / NPB, blk, 0, stream>>>(
      (const unsigned short*)featB, features, rs, esrc, rsK, trip,
      (const unsigned short*)WmB, (const unsigned short*)W1B,
      (const unsigned short*)W2B, b1, b2, gamma, beta, out);
}